// Round 14
// baseline (170.014 us; speedup 1.0000x reference)
//
#include <hip/hip_runtime.h>
#include <math.h>

#define BS   16
#define NMAX 64
#define NA   8400
#define NCLS 80
#define TOPK 10
#define ROWS (BS * NMAX)          // 1024
#define TOTAL (BS * NA)           // 134400
#define NFIN (NMAX * TOPK)        // 640 per batch

typedef unsigned long long u64;

// CIoU (clipped at 0); at/area of both boxes precomputed by caller
__device__ __forceinline__ float ciou_clip(
    float gx1, float gy1, float gx2, float gy2, float at1, float area1,
    float px1, float py1, float px2, float py2, float at2, float area2)
{
    float iw = fminf(gx2, px2) - fmaxf(gx1, px1);
    float ih = fminf(gy2, py2) - fmaxf(gy1, py1);
    float inter = fmaxf(iw, 0.f) * fmaxf(ih, 0.f);
    float uni = area1 + area2 - inter + 1e-7f;
    float iou = inter / uni;
    float cw = fmaxf(gx2, px2) - fminf(gx1, px1);
    float ch = fmaxf(gy2, py2) - fminf(gy1, py1);
    float c2 = cw * cw + ch * ch + 1e-7f;
    float dx = px1 + px2 - gx1 - gx2;
    float dy = py1 + py2 - gy1 - gy2;
    float rho2 = (dx * dx + dy * dy) * 0.25f;
    float dat = at2 - at1;
    float v = (4.0f / (float)(M_PI * M_PI)) * dat * dat;
    float alpha = v / (v - iou + (1.0f + 1e-7f));
    return fmaxf(iou - (rho2 / c2 + v * alpha), 0.f);
}

#define INS10(kk)                                                         \
    if ((kk) > L[9]) {                                                    \
        L[9] = (kk);                                                      \
        _Pragma("unroll")                                                 \
        for (int q = 9; q >= 1; q--)                                      \
            if (L[q] > L[q-1]) { u64 tt = L[q-1]; L[q-1] = L[q]; L[q] = tt; } \
    }

// ---- k1: one block (2 waves) per row -> dense winner list fin_* ----
__global__ __launch_bounds__(128) void k1_rows(
    const float* __restrict__ score,
    const float* __restrict__ p_box,
    const int*   __restrict__ gt_labels,
    const float* __restrict__ gt_box,
    const float* __restrict__ mask,
    int*   __restrict__ fin_a,       // (ROWS,10): anchor or -1
    float* __restrict__ fin_mt,      // (ROWS,10)
    float* __restrict__ fin_ov,      // (ROWS,10)
    float* __restrict__ pos_mt,      // (ROWS) zeroed here
    float* __restrict__ pos_ov)      // (ROWS) zeroed here
{
    int row = blockIdx.x;
    int tid = threadIdx.x;
    if (tid == 0) { pos_mt[row] = 0.f; pos_ov[row] = 0.f; }
    if (mask[row] <= 0.f) {
        if (tid < TOPK) fin_a[row * TOPK + tid] = -1;
        return;
    }
    int wid  = tid >> 6;
    int lane = tid & 63;
    int b = row >> 6;

    float4 gb = ((const float4*)gt_box)[row];
    float w1 = gb.z - gb.x;
    float h1 = gb.w - gb.y + 1e-7f;
    float at1 = atanf(w1 / h1);
    float area1 = w1 * h1;
    int lbl = gt_labels[row];
    const float* sc = score + (size_t)b * NA * NCLS + lbl;
    const float4* pb = (const float4*)p_box + (size_t)b * NA;

    // padded candidate rects per level (exact test done per cell)
    int ilo0 = max(0,  (int)floorf(gb.x * 0.125f   - 0.5f));
    int ihi0 = min(79, (int)ceilf (gb.z * 0.125f   - 0.5f));
    int jlo0 = max(0,  (int)floorf(gb.y * 0.125f   - 0.5f));
    int jhi0 = min(79, (int)ceilf (gb.w * 0.125f   - 0.5f));
    int ilo1 = max(0,  (int)floorf(gb.x * 0.0625f  - 0.5f));
    int ihi1 = min(39, (int)ceilf (gb.z * 0.0625f  - 0.5f));
    int jlo1 = max(0,  (int)floorf(gb.y * 0.0625f  - 0.5f));
    int jhi1 = min(39, (int)ceilf (gb.w * 0.0625f  - 0.5f));
    int ilo2 = max(0,  (int)floorf(gb.x * 0.03125f - 0.5f));
    int ihi2 = min(19, (int)ceilf (gb.z * 0.03125f - 0.5f));
    int jlo2 = max(0,  (int)floorf(gb.y * 0.03125f - 0.5f));
    int jhi2 = min(19, (int)ceilf (gb.w * 0.03125f - 0.5f));
    int nx0 = max(0, ihi0 - ilo0 + 1), ny0 = max(0, jhi0 - jlo0 + 1);
    int nx1 = max(0, ihi1 - ilo1 + 1), ny1 = max(0, jhi1 - jlo1 + 1);
    int nx2 = max(0, ihi2 - ilo2 + 1), ny2 = max(0, jhi2 - jlo2 + 1);
    int c0 = nx0 * ny0;
    int c1 = c0 + nx1 * ny1;
    int T  = c1 + nx2 * ny2;

    u64 L[10];
#pragma unroll
    for (int q = 0; q < 10; q++) L[q] = 0ull;

    for (int t = tid; t < T; t += 128) {
        bool ge1 = t >= c0, ge2 = t >= c1;
        int local = t - (ge2 ? c1 : (ge1 ? c0 : 0));
        int nxl  = ge2 ? nx2  : (ge1 ? nx1  : nx0);
        int ilol = ge2 ? ilo2 : (ge1 ? ilo1 : ilo0);
        int jlol = ge2 ? jlo2 : (ge1 ? jlo1 : jlo0);
        int g    = ge2 ? 20   : (ge1 ? 40   : 80);
        int off  = ge2 ? 8000 : (ge1 ? 6400 : 0);
        float s  = ge2 ? 32.f : (ge1 ? 16.f : 8.f);
        int jj = local / nxl;
        int ii = local - jj * nxl;
        int i = ilol + ii, j = jlol + jj;
        int a = off + j * g + i;
        float ax = ((float)i + 0.5f) * s, ay = ((float)j + 0.5f) * s;
        float dmin = fminf(fminf(ax - gb.x, ay - gb.y),
                           fminf(gb.z - ax, gb.w - ay));
        if (dmin > 1e-9f) {
            float4 pv = pb[a];
            float w2 = pv.z - pv.x;
            float h2 = pv.w - pv.y + 1e-7f;
            float ov = ciou_clip(gb.x, gb.y, gb.z, gb.w, at1, area1,
                                 pv.x, pv.y, pv.z, pv.w,
                                 atanf(w2 / h2), w2 * h2);
            float o2 = ov * ov;
            float mt = sqrtf(sc[(size_t)a * NCLS]) * o2 * o2 * o2;
            u64 kk = ((u64)__float_as_uint(mt) << 32) | (unsigned)(~a);
            INS10(kk)
        }
    }
    // zero-metric tie fillers (wave 0 only): first 64 anchors, outside-box.
    // >=32 are outside (box width <256 px covers <=32 stride-8 cols), covering
    // all index-ordered zero-tie selections of lax.top_k.
    if (wid == 0) {
        float ax = (float)lane * 8.f + 4.f, ay = 4.f;
        float dmin = fminf(fminf(ax - gb.x, ay - gb.y),
                           fminf(gb.z - ax, gb.w - ay));
        if (!(dmin > 1e-9f)) {
            u64 kk = (u64)(unsigned)(~lane);
            INS10(kk)
        }
    }

    // per-wave top-10 -> LDS
    __shared__ u64 skey[2 * TOPK];
    u64 wk = 0ull;
    for (int it = 0; it < TOPK; it++) {
        u64 m = L[0];
#pragma unroll
        for (int o = 1; o < 64; o <<= 1) {
            u64 v = __shfl_xor(m, o);
            if (v > m) m = v;
        }
        if (lane == it) wk = m;
        if (L[0] == m) {
#pragma unroll
            for (int q = 0; q < 9; q++) L[q] = L[q + 1];
            L[9] = 0ull;
        }
    }
    if (lane < TOPK) skey[wid * TOPK + lane] = wk;
    __syncthreads();

    // wave 0 merges 20 candidates -> final 10; write dense fin list
    if (wid == 0) {
        u64 ck = (lane < 2 * TOPK) ? skey[lane] : 0ull;
        u64 winkey = 0ull;
        for (int it = 0; it < TOPK; it++) {
            u64 m = ck;
#pragma unroll
            for (int o = 1; o < 64; o <<= 1) {
                u64 v = __shfl_xor(m, o);
                if (v > m) m = v;
            }
            if (lane == it) winkey = m;
            if (ck == m) ck = 0ull;
        }
        if (lane < TOPK) {
            int slot = row * TOPK + lane;
            int fa = -1;
            if (winkey) {
                int a = (int)(~(unsigned)(winkey & 0xffffffffu));
                float mt = __uint_as_float((unsigned)(winkey >> 32));
                bool l2a = a >= 8000, l1a = (a >= 6400) && !l2a;
                int loc = a - (l2a ? 8000 : (l1a ? 6400 : 0));
                int g   = l2a ? 20 : (l1a ? 40 : 80);
                float s = l2a ? 32.f : (l1a ? 16.f : 8.f);
                int j = loc / g, i = loc - j * g;
                float ax = ((float)i + 0.5f) * s, ay = ((float)j + 0.5f) * s;
                float dmin = fminf(fminf(ax - gb.x, ay - gb.y),
                                   fminf(gb.z - ax, gb.w - ay));
                if (dmin > 1e-9f) {          // mask_in_gts re-check
                    fa = a;
                    float4 pv = pb[a];
                    float w2 = pv.z - pv.x;
                    float h2 = pv.w - pv.y + 1e-7f;
                    float ov = ciou_clip(gb.x, gb.y, gb.z, gb.w, at1, area1,
                                         pv.x, pv.y, pv.z, pv.w,
                                         atanf(w2 / h2), w2 * h2);
                    fin_mt[slot] = mt;
                    fin_ov[slot] = ov;
                }
            }
            fin_a[slot] = fa;
        }
    }
}

// ---- k3: per-anchor resolve via LDS broadcast of the batch fin list ----
__global__ __launch_bounds__(256) void k3_resolve(
    const float* __restrict__ score,
    const float* __restrict__ p_box,
    const float* __restrict__ anchors,
    const int*   __restrict__ gt_labels,
    const float* __restrict__ gt_box,
    const float* __restrict__ mask,
    const int*   __restrict__ fin_a,
    const float* __restrict__ fin_mt,
    const float* __restrict__ fin_ov,
    int* __restrict__ gt_idx,
    unsigned char* __restrict__ fg_arr,
    float* __restrict__ tgt_mt,
    float* __restrict__ out_bbox,
    float* __restrict__ out_fg,
    float* __restrict__ pos_mt,      // int-atomicMax on float bits (>=0)
    float* __restrict__ pos_ov)
{
    int b   = blockIdx.y;
    int a   = blockIdx.x * 256 + threadIdx.x;

    __shared__ int   s_fa[NFIN];
    __shared__ float s_mt[NFIN];
    __shared__ float s_ov[NFIN];
    for (int e = threadIdx.x; e < NFIN; e += 256) {
        s_fa[e] = fin_a[b * NFIN + e];
        s_mt[e] = fin_mt[b * NFIN + e];
        s_ov[e] = fin_ov[b * NFIN + e];
    }
    __syncthreads();
    if (a >= NA) return;
    int i = b * NA + a;

    u64 bits = 0ull;
    float mt = 0.f, ov = 0.f;
    {
        int e = 0;
        for (int r = 0; r < NMAX; r++) {
            u64 bit = 1ull << r;
#pragma unroll
            for (int s = 0; s < TOPK; s++, e++) {
                if (s_fa[e] == a) { bits |= bit; mt = s_mt[e]; ov = s_ov[e]; }
            }
        }
    }
    int fg0 = __popcll(bits);
    int gi = 0, fg = (fg0 > 0);
    if (fg0 == 1) {
        gi = __ffsll(bits) - 1;
    } else if (fg0 > 1) {
        float2 axy = ((const float2*)anchors)[a];
        float4 pv = ((const float4*)p_box)[i];
        float w2 = pv.z - pv.x;
        float h2 = pv.w - pv.y + 1e-7f;
        float at2 = atanf(w2 / h2);
        float area2 = w2 * h2;
        const float* mrow = mask + b * NMAX;
        float best = -1.f; int argn = 0;
        for (int nn = 0; nn < NMAX; nn++) {
            float v = 0.f;
            if (mrow[nn] > 0.f) {
                int r = b * NMAX + nn;
                float4 gbv = ((const float4*)gt_box)[r];
                float dmin = fminf(fminf(axy.x - gbv.x, axy.y - gbv.y),
                                   fminf(gbv.z - axy.x, gbv.w - axy.y));
                if (dmin > 1e-9f) {
                    float w1 = gbv.z - gbv.x;
                    float h1 = gbv.w - gbv.y + 1e-7f;
                    v = ciou_clip(gbv.x, gbv.y, gbv.z, gbv.w,
                                  atanf(w1 / h1), w1 * h1,
                                  pv.x, pv.y, pv.z, pv.w, at2, area2);
                }
            }
            if (v > best) { best = v; argn = nn; }
        }
        gi = argn;
        ov = fmaxf(best, 0.f);
        int lbl = gt_labels[b * NMAX + argn]; if (lbl < 0) lbl = 0;
        float gath = score[((size_t)b * NA + a) * NCLS + lbl];
        float o2 = ov * ov;
        mt = sqrtf(gath) * o2 * o2 * o2;
    } else {
        mt = 0.f; ov = 0.f;
    }
    int r = b * NMAX + gi;
    gt_idx[i] = gi;
    fg_arr[i] = (unsigned char)fg;
    tgt_mt[i] = fg ? mt : 0.f;
    out_fg[i] = fg ? 1.f : 0.f;
    ((float4*)out_bbox)[i] = ((const float4*)gt_box)[r];
    if (fg) {
        atomicMax((int*)&pos_mt[r], __float_as_int(mt));
        atomicMax((int*)&pos_ov[r], __float_as_int(ov));
    }
}

// ---- k5: full score tensor write (zeros + sparse values), float4 lanes ----
__global__ __launch_bounds__(256) void k5_full(
    const int*   __restrict__ gt_idx,
    const unsigned char* __restrict__ fg_arr,
    const float* __restrict__ tgt_mt,
    const int*   __restrict__ gt_labels,
    const float* __restrict__ pos_mt,
    const float* __restrict__ pos_ov,
    float4* __restrict__ out_scores)     // TOTAL*NCLS/4 float4s
{
    int i = blockIdx.x * 256 + threadIdx.x;
    if (i >= TOTAL * (NCLS / 4)) return;
    int ba = i / (NCLS / 4);
    int c4 = (i - ba * (NCLS / 4)) * 4;
    float4 o = make_float4(0.f, 0.f, 0.f, 0.f);
    if (fg_arr[ba]) {
        int b = ba / NA;
        int r = b * NMAX + gt_idx[ba];
        int lbl = gt_labels[r]; if (lbl < 0) lbl = 0;
        if (lbl >= c4 && lbl < c4 + 4) {
            float val = tgt_mt[ba] * pos_ov[r] / (pos_mt[r] + 1e-9f);
            if (lbl == c4)     o.x = val;
            if (lbl == c4 + 1) o.y = val;
            if (lbl == c4 + 2) o.z = val;
            if (lbl == c4 + 3) o.w = val;
        }
    }
    out_scores[i] = o;
}

extern "C" void kernel_launch(void* const* d_in, const int* in_sizes, int n_in,
                              void* d_out, int out_size, void* d_ws, size_t ws_size,
                              hipStream_t stream) {
    (void)in_sizes; (void)n_in; (void)out_size; (void)ws_size;
    const float* score     = (const float*)d_in[0];
    const float* p_box     = (const float*)d_in[1];
    const float* anchors   = (const float*)d_in[2];
    const int*   gt_labels = (const int*)d_in[3];
    const float* gt_box    = (const float*)d_in[4];
    const float* mask      = (const float*)d_in[5];

    char* w = (char*)d_ws;
    int*   fin_a    = (int*)w;                 w += (size_t)ROWS * TOPK * 4;
    float* fin_mt   = (float*)w;               w += (size_t)ROWS * TOPK * 4;
    float* fin_ov   = (float*)w;               w += (size_t)ROWS * TOPK * 4;
    float* pos_mt   = (float*)w;               w += (size_t)ROWS * 4;
    float* pos_ov   = (float*)w;               w += (size_t)ROWS * 4;
    int*   gt_idx   = (int*)w;                 w += (size_t)TOTAL * 4;
    float* tgt_mt   = (float*)w;               w += (size_t)TOTAL * 4;
    unsigned char* fg_arr = (unsigned char*)w; w += (size_t)TOTAL;

    float*  out_bbox   = (float*)d_out;                        // BS*NA*4
    float4* out_scores = (float4*)(out_bbox + (size_t)TOTAL * 4);
    float*  out_fg     = (float*)out_scores + (size_t)TOTAL * NCLS; // BS*NA

    hipLaunchKernelGGL(k1_rows, dim3(ROWS), dim3(128), 0, stream,
                       score, p_box, gt_labels, gt_box, mask,
                       fin_a, fin_mt, fin_ov, pos_mt, pos_ov);
    hipLaunchKernelGGL(k3_resolve, dim3((NA + 255) / 256, BS), dim3(256), 0, stream,
                       score, p_box, anchors, gt_labels, gt_box, mask,
                       fin_a, fin_mt, fin_ov,
                       gt_idx, fg_arr, tgt_mt, out_bbox, out_fg, pos_mt, pos_ov);
    hipLaunchKernelGGL(k5_full, dim3((TOTAL * (NCLS / 4) + 255) / 256), dim3(256), 0, stream,
                       gt_idx, fg_arr, tgt_mt, gt_labels, pos_mt, pos_ov,
                       (float4*)out_scores);
}